// Round 20
// baseline (122.123 us; speedup 1.0000x reference)
//
#include <hip/hip_runtime.h>
#include <hip/hip_bf16.h>

typedef __attribute__((ext_vector_type(8))) short short8;
typedef __attribute__((ext_vector_type(4))) float f32x4;

#define NTOK   100000
#define H      150
#define NKS    20          // K-slabs; float windows start {0,32,64,96,118} (all in-row)
#define BM     128
#define XBYT   16384       // 128 rows x 32 floats
#define LBUF   26624       // XBYT + 10KB B per slab; 3 slots = 79872 <= 81920
#define OUTOFF (NTOK * H)
#define AS1 __attribute__((address_space(1)))
#define AS3 __attribute__((address_space(3)))

__device__ __forceinline__ unsigned short f2bf(float f) {
    unsigned int u = __builtin_bit_cast(unsigned int, f);
    u = (u + 0x7FFFu + ((u >> 16) & 1u)) >> 16;   // RNE
    return (unsigned short)u;
}

template<int N> __device__ __forceinline__ void vwait() {
    if constexpr (N == 4)       asm volatile("s_waitcnt vmcnt(4)" ::: "memory");
    else if constexpr (N == 3)  asm volatile("s_waitcnt vmcnt(3)" ::: "memory");
    else if constexpr (N == 44) asm volatile("s_waitcnt vmcnt(44)" ::: "memory");
    else if constexpr (N == 43) asm volatile("s_waitcnt vmcnt(43)" ::: "memory");
    else if constexpr (N == 40) asm volatile("s_waitcnt vmcnt(40)" ::: "memory");
    else                        asm volatile("s_waitcnt vmcnt(0)" ::: "memory");
}

// ---------------------------------------------------------------------------
// Prepass (unchanged from r19): pack weights K-SLAB-major:
// wb[((ks*10 + n)*64 + lane)*8 + j]. Window: s5<4 -> k2 = s5*32 + p;
// s5==4 -> k2 = 118 + p (in-row), p<10 zeroed (overlap). col>=150 zeroed.
// ---------------------------------------------------------------------------
__global__ void prep_w(const float* __restrict__ w_in, const float* __restrict__ w_out,
                       const float* __restrict__ u_in, const float* __restrict__ u_out,
                       unsigned short* __restrict__ wb) {
    int idx = blockIdx.x * 256 + threadIdx.x;
    if (idx >= NKS * 10 * 512) return;           // 102400 elems
    int j    = idx & 7;
    int lane = (idx >> 3) & 63;
    int n    = (idx >> 9) % 10;
    int ks   = idx / 5120;
    int seg  = ks / 5, s5 = ks % 5;
    int col  = n * 16 + (lane & 15);
    int p    = (lane >> 4) * 8 + j;
    int k2   = (s5 < 4) ? (s5 * 32 + p) : (118 + p);
    float v = 0.0f;
    if (col < H && !(s5 == 4 && p < 10)) {
        const float* W = (seg == 0) ? w_in : (seg == 1) ? w_out : (seg == 2) ? u_in : u_out;
        v = W[k2 * H + col];
    }
    wb[idx] = f2bf(v);
}

// ---------------------------------------------------------------------------
// Main fused kernel: BM=128, ring-3 K-slab LDS pipeline (r19 schedule at 2x
// tile). 8 waves (4M x 2N), each wave 32 rows x 80 cols, acc[2][5]. Per iter:
//   vwait(c_w) -> s_barrier -> stage(ks+2) -> compute(ks)
// Half the blocks (782) and 2x compute per barrier vs r19; cover for slab
// ks+1 = 2 big phases. lc prefetch (40/thread) at ks=17, FIFO-counted.
// ---------------------------------------------------------------------------
__global__ __launch_bounds__(512, 4) void lstm_fused(
        const float* __restrict__ s_in, const float* __restrict__ s_out,
        const float* __restrict__ h_in, const float* __restrict__ h_out,
        const float* __restrict__ last_c, const unsigned short* __restrict__ wb,
        float* __restrict__ out) {
    __shared__ __align__(16) char lds[3 * LBUF];   // 79872 B -> 2 blocks/CU

    const int t     = threadIdx.x;
    const int lane  = t & 63;
    const int wid   = t >> 6;       // 0..7
    const int waveM = wid >> 1;     // 0..3 -> rows waveM*32 + [0,32)
    const int waveN = wid & 1;      // cols waveN*80 + [0,80)
    const int lrow  = lane & 15;
    const int lko   = lane >> 4;
    const int r0blk = blockIdx.x * BM;
    const bool cw3  = (wid < 2);    // waves 0,1: 4 chunks/slab; others: 3

    const float* Xseg[4] = {s_in, s_out, h_in, h_out};

    f32x4 acc[2][5];
#pragma unroll
    for (int m = 0; m < 2; m++)
#pragma unroll
        for (int n = 0; n < 5; n++) acc[m][n] = (f32x4){0.f, 0.f, 0.f, 0.f};

    float lcv[2][4][5];   // prefetched last_c

    // ---- stage one K-slab: X 16KB as 16 chunks (2/wave), B 10KB as 10 ----
    auto stage = [&](int ks2) {
        char* lb = &lds[(ks2 % 3) * LBUF];
        const int s5 = ks2 % 5;
        const int sofs = (s5 < 4) ? s5 * 128 : 472;   // in-row window offset
        const char* xb = (const char*)Xseg[ks2 / 5];
        const int q = (lane & 7) ^ ((lane >> 3) & 7); // XOR-swizzled source piece
#pragma unroll
        for (int h2 = 0; h2 < 2; h2++) {              // X chunks wid, wid+8
            const int c = wid + h2 * 8;
            int rowg = r0blk + c * 8 + (lane >> 3);
            if (rowg > NTOK - 1) rowg = NTOK - 1;     // tail block clamp (in-row)
            const long go = (long)rowg * 600 + sofs + q * 16;
            __builtin_amdgcn_global_load_lds(
                (const AS1 void*)(xb + go),
                (AS3 void*)(lb + c * 1024 + lane * 16), 16, 0, 0);
        }
        const char* bsrc = (const char*)wb + (long)ks2 * 10240;
        __builtin_amdgcn_global_load_lds(
            (const AS1 void*)(bsrc + wid * 1024 + lane * 16),
            (AS3 void*)(lb + XBYT + wid * 1024 + lane * 16), 16, 0, 0);
        if (cw3)
            __builtin_amdgcn_global_load_lds(
                (const AS1 void*)(bsrc + (8 + wid) * 1024 + lane * 16),
                (AS3 void*)(lb + XBYT + (8 + wid) * 1024 + lane * 16), 16, 0, 0);
    };

    // ---- compute one K-slab: pure LDS + VALU + MFMA ----
    auto compute = [&](int ks2) {
        const char* lb = &lds[(ks2 % 3) * LBUF];
        const char* br = lb + XBYT + (waveN * 5) * 1024 + lane * 16;
        short8 af[2];
#pragma unroll
        for (int m = 0; m < 2; m++) {
            const int row = waveM * 32 + m * 16 + lrow;
            const int r7 = row & 7;
            const char* xr = lb + row * 128;
            f32x4 v0 = *(const f32x4*)(xr + ((((lko << 1) | 0) ^ r7) << 4));
            f32x4 v1 = *(const f32x4*)(xr + ((((lko << 1) | 1) ^ r7) << 4));
            af[m][0] = (short)f2bf(v0[0]); af[m][1] = (short)f2bf(v0[1]);
            af[m][2] = (short)f2bf(v0[2]); af[m][3] = (short)f2bf(v0[3]);
            af[m][4] = (short)f2bf(v1[0]); af[m][5] = (short)f2bf(v1[1]);
            af[m][6] = (short)f2bf(v1[2]); af[m][7] = (short)f2bf(v1[3]);
        }
        __builtin_amdgcn_s_setprio(1);
#pragma unroll
        for (int n = 0; n < 5; n++) {
            short8 bf = *(const short8*)(br + n * 1024);
            acc[0][n] = __builtin_amdgcn_mfma_f32_16x16x32_bf16(af[0], bf, acc[0][n], 0, 0, 0);
            acc[1][n] = __builtin_amdgcn_mfma_f32_16x16x32_bf16(af[1], bf, acc[1][n], 0, 0, 0);
        }
        __builtin_amdgcn_s_setprio(0);
    };

    // ---- prologue: fill ring to depth 2 ----
    stage(0); stage(1);

#pragma unroll
    for (int ks = 0; ks < NKS; ks++) {
        if (ks < NKS - 2)       { if (cw3) vwait<4>();  else vwait<3>();  }
        else if (ks == NKS - 2) { if (cw3) vwait<44>(); else vwait<43>(); }
        else                    vwait<40>();
        __builtin_amdgcn_s_barrier();
        asm volatile("" ::: "memory");   // no LDS-read hoisting above the barrier

        if (ks < NKS - 2) stage(ks + 2);

        if (ks == NKS - 3) {
            __builtin_amdgcn_sched_barrier(0);   // pin: stage(19) before lc loads
            // prefetch last_c: 40 unconditional clamped loads (exact FIFO count)
#pragma unroll
            for (int m = 0; m < 2; m++)
#pragma unroll
                for (int r = 0; r < 4; r++) {
                    int row = r0blk + waveM * 32 + m * 16 + lko * 4 + r;
                    if (row > NTOK - 1) row = NTOK - 1;
#pragma unroll
                    for (int n = 0; n < 5; n++) {
                        int col = waveN * 80 + n * 16 + lrow;
                        if (col >= H) col = 0;
                        lcv[m][r][n] = last_c[(long)row * H + col];
                    }
                }
            __builtin_amdgcn_sched_barrier(0);   // pin: lc loads before compute
        }

        compute(ks);
    }

    vwait<0>();   // lc loads landed

    // ---- fused epilogue: g=sigmoid(pre); cell=g*lc+g*g; hid=g*tanh(cell)
#pragma unroll
    for (int m = 0; m < 2; m++) {
#pragma unroll
        for (int r = 0; r < 4; r++) {
            const int row = r0blk + waveM * 32 + m * 16 + lko * 4 + r;
            if (row >= NTOK) continue;
            const long rb = (long)row * H;
#pragma unroll
            for (int n = 0; n < 5; n++) {
                const int col = waveN * 80 + n * 16 + lrow;
                if (col >= H) continue;
                float pre = acc[m][n][r];
                float e   = __expf(-pre);
                float g   = __builtin_amdgcn_rcpf(1.f + e);
                float cell = g * lcv[m][r][n] + g * g;
                float e2  = __expf(-2.f * cell);
                float th  = (1.f - e2) * __builtin_amdgcn_rcpf(1.f + e2);
                out[rb + col]          = g * th;
                out[OUTOFF + rb + col] = cell;
            }
        }
    }
}

extern "C" void kernel_launch(void* const* d_in, const int* in_sizes, int n_in,
                              void* d_out, int out_size, void* d_ws, size_t ws_size,
                              hipStream_t stream) {
    const float* s_in   = (const float*)d_in[0];
    const float* s_out  = (const float*)d_in[1];
    const float* h_in   = (const float*)d_in[2];
    const float* h_out  = (const float*)d_in[3];
    const float* last_c = (const float*)d_in[4];
    const float* w_in   = (const float*)d_in[5];
    const float* w_out  = (const float*)d_in[6];
    const float* u_in   = (const float*)d_in[7];
    const float* u_out  = (const float*)d_in[8];

    unsigned short* wb = (unsigned short*)d_ws;   // 204800 B
    float* out = (float*)d_out;

    prep_w<<<(NKS * 10 * 512 + 255) / 256, 256, 0, stream>>>(w_in, w_out, u_in, u_out, wb);

    const int nblocks = (NTOK + BM - 1) / BM;  // 782 blocks, 8 waves (4Mx2N)
    lstm_fused<<<nblocks, 512, 0, stream>>>(s_in, s_out, h_in, h_out, last_c, wb, out);
}